// Round 3
// baseline (140.936 us; speedup 1.0000x reference)
//
#include <hip/hip_runtime.h>
#include <hip/hip_bf16.h>

#define NPTS 524288
#define DIM 256
#define KC 64

typedef __attribute__((ext_vector_type(8))) short bf16x8;
typedef __attribute__((ext_vector_type(4))) float f32x4;

typedef __attribute__((address_space(1))) const unsigned int GUI;
typedef __attribute__((address_space(3))) unsigned int LUI;

static __device__ __forceinline__ void gload16(const void* g, void* l) {
  __builtin_amdgcn_global_load_lds((GUI*)g, (LUI*)l, 16, 0, 0);
}

static __device__ __forceinline__ ushort f32_to_bf16_rne(float f) {
  unsigned int b = __builtin_bit_cast(unsigned int, f);
  b += 0x7FFFu + ((b >> 16) & 1u);   // RNE; inputs finite
  return (ushort)(b >> 16);
}

// ws image (32 KiB): slot s holds cluster 4*(s%16)+s/16; 16-B granule m of slot s
// lives at byte s*512 + ((m ^ (s&7))<<4). c2 (natural cluster order) at +32768.
__global__ void prep_clusters(const float* __restrict__ C,
                              char* __restrict__ cb,
                              float* __restrict__ c2) {
  const int w = threadIdx.x >> 6;
  const int lane = threadIdx.x & 63;
  const int k = blockIdx.x * 8 + w * 2 + (lane >> 5);  // cluster
  const int m = lane & 31;                             // 16-B granule (8 elems)
  const float* src = C + k * DIM + m * 8;
  float4 u0 = ((const float4*)src)[0];
  float4 u1 = ((const float4*)src)[1];
  float vv[8] = {u0.x, u0.y, u0.z, u0.w, u1.x, u1.y, u1.z, u1.w};
  float s = 0.f;
  bf16x8 h;
#pragma unroll
  for (int j = 0; j < 8; ++j) {
    s = fmaf(vv[j], vv[j], s);
    h[j] = (short)f32_to_bf16_rne(vv[j]);
  }
  s += __shfl_xor(s, 1);
  s += __shfl_xor(s, 2);
  s += __shfl_xor(s, 4);
  s += __shfl_xor(s, 8);
  s += __shfl_xor(s, 16);
  const int slot = 16 * (k & 3) + (k >> 2);
  const int off = slot * 512 + ((m ^ (slot & 7)) << 4);
  *(bf16x8*)(cb + off) = h;
  if (m == 0) c2[k] = s;
}

// Block: 4 waves, 256 rows in 4 passes of 64 (16/wave/pass), all 64 cols.
// B persistent in LDS[0,32K); A wave-private dbuf at 32768+w*8192, halves of 4K.
// Chunk ci (0..15): pass ci>>2, K-quarter ci&3, LDS half ci&1.
// 16 rows x 64 fp32 per chunk; within a row, 16-B granule m holds logical
// granule m ^ (row&7) (source pre-swizzled, linear global_load_lds dest).
__global__ __launch_bounds__(256, 2)
void cluster_q(const float* __restrict__ A, const char* __restrict__ cb,
               const float* __restrict__ c2, float* __restrict__ out) {
  __shared__ char lds[65536];
  const int tid = threadIdx.x;
  const int lane = tid & 63;
  const int w = tid >> 6;
  const int l15 = lane & 15;
  const int g = lane >> 4;
  const long brow = (long)blockIdx.x * 256;

  // ---- stage B once per block: 32 KiB linear copy (image pre-permuted+swizzled)
  {
    const char* src = cb + w * 8192 + lane * 16;
    char* dst = lds + w * 8192;
#pragma unroll
    for (int i = 0; i < 8; ++i)
      gload16(src + i * 1024, dst + i * 1024);
  }

  const char* Abase = (const char*)A + (brow + w * 16) * 1024;  // pass0 row-group

#define STAGE(ci)                                                            \
  do {                                                                       \
    char* dbase = lds + 32768 + w * 8192 + ((ci) & 1) * 4096;                \
    const char* sbase = Abase + ((ci) >> 2) * 65536 + ((ci) & 3) * 256;      \
    _Pragma("unroll") for (int c4 = 0; c4 < 4; ++c4) {                       \
      int o = c4 * 1024 + lane * 16;                                         \
      int row = o >> 8;                                                      \
      int swz = ((((o >> 4) & 15) ^ (row & 7)) << 4);                        \
      gload16(sbase + row * 1024 + swz, dbase + c4 * 1024);                  \
    }                                                                        \
  } while (0)

#define KSTEP(c, s2)                                                         \
  do {                                                                       \
    const char* abuf = lds + 32768 + w * 8192 + ((c) & 1) * 4096;            \
    int ga = (s2) * 8 + g * 2;                                               \
    int a0 = l15 * 256 + ((ga ^ (l15 & 7)) << 4);                            \
    float4 u0 = *(const float4*)(abuf + a0);                                 \
    float4 u1 = *(const float4*)(abuf + (a0 ^ 16));                          \
    float vv[8] = {u0.x, u0.y, u0.z, u0.w, u1.x, u1.y, u1.z, u1.w};          \
    bf16x8 af;                                                               \
    _Pragma("unroll") for (int j = 0; j < 8; ++j) {                          \
      x2l = fmaf(vv[j], vv[j], x2l);                                         \
      af[j] = (short)f32_to_bf16_rne(vv[j]);                                 \
    }                                                                        \
    int ks = ((c) & 3) * 2 + (s2);                                           \
    _Pragma("unroll") for (int t = 0; t < 4; ++t) {                          \
      int slot = l15 + 16 * t;                                               \
      bf16x8 bf = *(const bf16x8*)(lds + slot * 512 +                        \
                                   (((ks * 4 + g) ^ (slot & 7)) << 4));      \
      acc[t] = __builtin_amdgcn_mfma_f32_16x16x32_bf16(af, bf, acc[t], 0, 0, 0); \
    }                                                                        \
  } while (0)

#define CHUNK(c)                                                             \
  do {                                                                       \
    KSTEP(c, 0);                                                             \
    KSTEP(c, 1);                                                             \
    if ((c) + 2 < 16) STAGE((c) + 2);                                        \
  } while (0)

#define V0 asm volatile("s_waitcnt vmcnt(0)" ::: "memory")
#define V4 asm volatile("s_waitcnt vmcnt(4)" ::: "memory")
#define V8 asm volatile("s_waitcnt vmcnt(8)" ::: "memory")

#define INIT                                                                 \
  do {                                                                       \
    _Pragma("unroll") for (int t = 0; t < 4; ++t)                            \
        acc[t] = (f32x4){0.f, 0.f, 0.f, 0.f};                                \
    x2l = 0.f;                                                               \
  } while (0)

#define EPI(p)                                                               \
  do {                                                                       \
    x2l += __shfl_xor(x2l, 16);                                              \
    x2l += __shfl_xor(x2l, 32);                                              \
    float x2r[4];                                                            \
    _Pragma("unroll") for (int r = 0; r < 4; ++r)                            \
        x2r[r] = __shfl(x2l, g * 4 + r);                                     \
    float4 c2v = *(const float4*)(c2 + 4 * l15);                             \
    float c2a[4] = {c2v.x, c2v.y, c2v.z, c2v.w};                             \
    float qv[4][4];                                                          \
    float rsum[4] = {0.f, 0.f, 0.f, 0.f};                                    \
    _Pragma("unroll") for (int t = 0; t < 4; ++t) {                          \
      _Pragma("unroll") for (int r = 0; r < 4; ++r) {                        \
        float d2 = fmaxf(x2r[r] + c2a[t] - 2.0f * acc[t][r], 0.f);           \
        float qq = __builtin_amdgcn_rcpf(1.0f + d2);                         \
        qv[t][r] = qq;                                                       \
        rsum[r] += qq;                                                       \
      }                                                                      \
    }                                                                        \
    _Pragma("unroll") for (int r = 0; r < 4; ++r) {                          \
      rsum[r] += __shfl_xor(rsum[r], 1);                                     \
      rsum[r] += __shfl_xor(rsum[r], 2);                                     \
      rsum[r] += __shfl_xor(rsum[r], 4);                                     \
      rsum[r] += __shfl_xor(rsum[r], 8);                                     \
      float inv = __builtin_amdgcn_rcpf(rsum[r]);                            \
      long orow = brow + (p) * 64 + w * 16 + g * 4 + r;                      \
      float4 o4 = {qv[0][r] * inv, qv[1][r] * inv, qv[2][r] * inv,           \
                   qv[3][r] * inv};                                          \
      *(float4*)(out + orow * 64 + 4 * l15) = o4;                            \
    }                                                                        \
  } while (0)

  f32x4 acc[4];
  float x2l;

  STAGE(0);
  STAGE(1);
  __syncthreads();  // sole full drain: B + chunks 0,1 resident

  // vmcnt accounting (queue is in-order; epilogue's 4 stores tick vmcnt too):
  // pass p>=1 entry queue = {S(4p), S(4p+1), ST(p-1)}.
  INIT;
  /*c0*/      CHUNK(0);
  /*c1*/      CHUNK(1);
  /*c2*/ V4;  CHUNK(2);
  /*c3*/ V4;  CHUNK(3);
  EPI(0);
  INIT;
  /*c4*/ V8;  CHUNK(4);
  /*c5*/ V8;  CHUNK(5);
  /*c6*/ V4;  CHUNK(6);
  /*c7*/ V4;  CHUNK(7);
  EPI(1);
  INIT;
  /*c8*/ V8;  CHUNK(8);
  /*c9*/ V8;  CHUNK(9);
  /*c10*/V4;  CHUNK(10);
  /*c11*/V4;  CHUNK(11);
  EPI(2);
  INIT;
  /*c12*/V8;  CHUNK(12);
  /*c13*/V8;  CHUNK(13);
  /*c14*/V4;  CHUNK(14);
  /*c15*/V0;  CHUNK(15);
  EPI(3);

#undef STAGE
#undef KSTEP
#undef CHUNK
#undef V0
#undef V4
#undef V8
#undef INIT
#undef EPI
}

extern "C" void kernel_launch(void* const* d_in, const int* in_sizes, int n_in,
                              void* d_out, int out_size, void* d_ws, size_t ws_size,
                              hipStream_t stream) {
  const float* inputs = (const float*)d_in[0];
  const float* clusters = (const float*)d_in[1];
  float* out = (float*)d_out;

  char* cb = (char*)d_ws;                      // 32 KiB pre-swizzled B image
  float* c2 = (float*)((char*)d_ws + 32768);   // 64 floats

  prep_clusters<<<8, 256, 0, stream>>>(clusters, cb, c2);
  cluster_q<<<NPTS / 256, 256, 0, stream>>>(inputs, cb, c2, out);
}

// Round 4
// 131.227 us; speedup vs baseline: 1.0740x; 1.0740x over previous
//
#include <hip/hip_runtime.h>
#include <hip/hip_bf16.h>

#define NPTS 524288
#define DIM 256
#define KC 64

typedef __attribute__((ext_vector_type(8))) short bf16x8;
typedef __attribute__((ext_vector_type(4))) float f32x4;

typedef __attribute__((address_space(1))) const unsigned int GUI;
typedef __attribute__((address_space(3))) unsigned int LUI;

static __device__ __forceinline__ void gload16(const void* g, void* l) {
  __builtin_amdgcn_global_load_lds((GUI*)g, (LUI*)l, 16, 0, 0);
}

static __device__ __forceinline__ ushort f32_to_bf16_rne(float f) {
  unsigned int b = __builtin_bit_cast(unsigned int, f);
  b += 0x7FFFu + ((b >> 16) & 1u);   // RNE; inputs finite
  return (ushort)(b >> 16);
}

static __device__ __forceinline__ short f2bf(float f) {
  return __builtin_bit_cast(short, __float2bfloat16(f));  // compiler fuses pairs to cvt_pk
}

// ws image (32 KiB): slot s holds cluster 4*(s%16)+s/16; 16-B granule m of slot s
// lives at byte s*512 + ((m ^ (s&7))<<4). c2 (natural cluster order) at +32768.
__global__ void prep_clusters(const float* __restrict__ C,
                              char* __restrict__ cb,
                              float* __restrict__ c2) {
  const int w = threadIdx.x >> 6;
  const int lane = threadIdx.x & 63;
  const int k = blockIdx.x * 8 + w * 2 + (lane >> 5);  // cluster
  const int m = lane & 31;                             // 16-B granule (8 elems)
  const float* src = C + k * DIM + m * 8;
  float4 u0 = ((const float4*)src)[0];
  float4 u1 = ((const float4*)src)[1];
  float vv[8] = {u0.x, u0.y, u0.z, u0.w, u1.x, u1.y, u1.z, u1.w};
  float s = 0.f;
  bf16x8 h;
#pragma unroll
  for (int j = 0; j < 8; ++j) {
    s = fmaf(vv[j], vv[j], s);
    h[j] = (short)f32_to_bf16_rne(vv[j]);
  }
  s += __shfl_xor(s, 1);
  s += __shfl_xor(s, 2);
  s += __shfl_xor(s, 4);
  s += __shfl_xor(s, 8);
  s += __shfl_xor(s, 16);
  const int slot = 16 * (k & 3) + (k >> 2);
  const int off = slot * 512 + ((m ^ (slot & 7)) << 4);
  *(bf16x8*)(cb + off) = h;
  if (m == 0) c2[k] = s;
}

// Block: 4 waves, 64 rows (16/wave), 64 cols. LDS = 32 KiB (B only) -> 4 blocks/CU.
// A goes global -> registers directly: lane (l15,g) reads rows l15, bytes
// ks*128 + g*32 .. +32 (two float4). Wave access = 16 x 128 B contiguous runs.
// Depth-2 prefetch over 3 rotating register buffers, fully unrolled.
__global__ __launch_bounds__(256, 4)
void cluster_q(const float* __restrict__ A, const char* __restrict__ cb,
               const float* __restrict__ c2, float* __restrict__ out) {
  __shared__ char lds[32768];
  const int tid = threadIdx.x;
  const int lane = tid & 63;
  const int w = tid >> 6;
  const int l15 = lane & 15;
  const int g = lane >> 4;
  const long brow = (long)blockIdx.x * 64;

  const char* Ap = (const char*)A + (brow + w * 16 + l15) * 1024 + g * 32;

  // prologue: A prefetch for ks=0,1 (HBM) issued before B stage (L2) so both overlap
  float4 b0a = *(const float4*)(Ap + 0 * 128);
  float4 b0b = *(const float4*)(Ap + 0 * 128 + 16);
  float4 b1a = *(const float4*)(Ap + 1 * 128);
  float4 b1b = *(const float4*)(Ap + 1 * 128 + 16);

  {
    const char* src = cb + w * 8192 + lane * 16;
    char* dst = lds + w * 8192;
#pragma unroll
    for (int i = 0; i < 8; ++i)
      gload16(src + i * 1024, dst + i * 1024);
  }
  __syncthreads();  // B resident (A ks0/ks1 also drained here)

  f32x4 acc[4];
#pragma unroll
  for (int t = 0; t < 4; ++t) acc[t] = (f32x4){0.f, 0.f, 0.f, 0.f};
  float x2l = 0.f;
  float4 b2a, b2b;

#define KSTEP(ks, CA, CB, PA, PB)                                            \
  do {                                                                       \
    float vv[8] = {CA.x, CA.y, CA.z, CA.w, CB.x, CB.y, CB.z, CB.w};          \
    if ((ks) + 2 < 8) {                                                      \
      PA = *(const float4*)(Ap + ((ks) + 2) * 128);                          \
      PB = *(const float4*)(Ap + ((ks) + 2) * 128 + 16);                     \
    }                                                                        \
    bf16x8 af;                                                               \
    _Pragma("unroll") for (int j = 0; j < 8; ++j) {                          \
      x2l = fmaf(vv[j], vv[j], x2l);                                         \
      af[j] = f2bf(vv[j]);                                                   \
    }                                                                        \
    _Pragma("unroll") for (int t = 0; t < 4; ++t) {                          \
      int slot = l15 + 16 * t;                                               \
      bf16x8 bf = *(const bf16x8*)(lds + slot * 512 +                        \
                                   ((((ks) * 4 + g) ^ (slot & 7)) << 4));    \
      acc[t] = __builtin_amdgcn_mfma_f32_16x16x32_bf16(af, bf, acc[t], 0, 0, 0); \
    }                                                                        \
  } while (0)

  // buffers rotate mod 3; prefetch target (ks+2)%3 never aliases ks%3 or (ks+1)%3
  KSTEP(0, b0a, b0b, b2a, b2b);
  KSTEP(1, b1a, b1b, b0a, b0b);
  KSTEP(2, b2a, b2b, b1a, b1b);
  KSTEP(3, b0a, b0b, b2a, b2b);
  KSTEP(4, b1a, b1b, b0a, b0b);
  KSTEP(5, b2a, b2b, b1a, b1b);
  KSTEP(6, b0a, b0b, b0a, b0b);  // ks+2 >= 8: no prefetch
  KSTEP(7, b1a, b1b, b0a, b0b);  // ks+2 >= 8: no prefetch
#undef KSTEP

  // ---- epilogue
  x2l += __shfl_xor(x2l, 16);
  x2l += __shfl_xor(x2l, 32);  // full ||x||^2 for row l15, replicated across g
  float x2r[4];
#pragma unroll
  for (int r = 0; r < 4; ++r) x2r[r] = __shfl(x2l, g * 4 + r);

  float4 c2v = *(const float4*)(c2 + 4 * l15);  // clusters 4*l15 .. +3  (== t)
  float c2a[4] = {c2v.x, c2v.y, c2v.z, c2v.w};

  float qv[4][4];
  float rsum[4] = {0.f, 0.f, 0.f, 0.f};
#pragma unroll
  for (int t = 0; t < 4; ++t) {
#pragma unroll
    for (int r = 0; r < 4; ++r) {
      float d2 = fmaxf(x2r[r] + c2a[t] - 2.0f * acc[t][r], 0.f);
      float qq = __builtin_amdgcn_rcpf(1.0f + d2);  // ALPHA=1, exponent 1
      qv[t][r] = qq;
      rsum[r] += qq;
    }
  }
#pragma unroll
  for (int r = 0; r < 4; ++r) {
    rsum[r] += __shfl_xor(rsum[r], 1);
    rsum[r] += __shfl_xor(rsum[r], 2);
    rsum[r] += __shfl_xor(rsum[r], 4);
    rsum[r] += __shfl_xor(rsum[r], 8);
    float inv = __builtin_amdgcn_rcpf(rsum[r]);
    long orow = brow + w * 16 + g * 4 + r;
    float4 o4 = {qv[0][r] * inv, qv[1][r] * inv, qv[2][r] * inv, qv[3][r] * inv};
    *(float4*)(out + orow * 64 + 4 * l15) = o4;  // lane holds clusters 4*l15..+3
  }
}

extern "C" void kernel_launch(void* const* d_in, const int* in_sizes, int n_in,
                              void* d_out, int out_size, void* d_ws, size_t ws_size,
                              hipStream_t stream) {
  const float* inputs = (const float*)d_in[0];
  const float* clusters = (const float*)d_in[1];
  float* out = (float*)d_out;

  char* cb = (char*)d_ws;                      // 32 KiB pre-swizzled B image
  float* c2 = (float*)((char*)d_ws + 32768);   // 64 floats

  prep_clusters<<<8, 256, 0, stream>>>(clusters, cb, c2);
  cluster_q<<<NPTS / 64, 256, 0, stream>>>(inputs, cb, c2, out);
}